// Round 1
// baseline (622.148 us; speedup 1.0000x reference)
//
#include <hip/hip_runtime.h>
#include <hip/hip_bf16.h>

#define N_ATOMS 30000
#define M_NBR   12
#define A_DIM   256
#define B_DIM   128
#define K1DIM   512

typedef __bf16 bf16x8 __attribute__((ext_vector_type(8)));
typedef float  f32x4  __attribute__((ext_vector_type(4)));

__device__ __forceinline__ unsigned short f2bf(float f) {
    union { float f; unsigned u; } v; v.f = f;
    unsigned r = v.u + 0x7fffu + ((v.u >> 16) & 1u);
    return (unsigned short)(r >> 16);
}
__device__ __forceinline__ float bf2f(unsigned short u) {
    union { unsigned u; float f; } v; v.u = ((unsigned)u) << 16;
    return v.f;
}

// ---------------- Kernel 0: pack fc_w into bf16 fragment-order tables ----------
// Wp1: [32][1024][8]  (K=256 granules g, cols n'<512 -> W[n'][g*8+j] ; n'>=512 -> W[n'-512][256+g*8+j])
// Wp3: [16][512][8]   (K=128 granules,  Wp3[g][n][j] = W[n][512+g*8+j])
__global__ void pack_weights(const float* __restrict__ fc_w,
                             unsigned short* __restrict__ Wp1,
                             unsigned short* __restrict__ Wp3) {
    int idx = blockIdx.x * 256 + threadIdx.x;
    const int n1 = 32 * 1024 * 8;
    if (idx < n1) {
        int j = idx & 7, n = (idx >> 3) & 1023, g = idx >> 13;
        float v = (n < 512) ? fc_w[n * 640 + g * 8 + j]
                            : fc_w[(n - 512) * 640 + 256 + g * 8 + j];
        Wp1[idx] = f2bf(v);
    } else {
        int k = idx - n1;
        if (k < 16 * 512 * 8) {
            int j = k & 7, n = (k >> 3) & 511, g = k >> 12;
            Wp3[k] = f2bf(fc_w[n * 640 + 512 + g * 8 + j]);
        }
    }
}

// ---------------- Kernel 1: P[n][0:512]=W1*atom+b, P[n][512:1024]=W2*atom (bf16) ---
__global__ __launch_bounds__(512, 2) void gemm_p(
    const float* __restrict__ atom, const float* __restrict__ fc_b,
    const unsigned short* __restrict__ Wp1, unsigned short* __restrict__ P)
{
    __shared__ unsigned short sA[128 * 256];   // 64KB, swizzled bf16 A-tile
    const int tid = threadIdx.x;
    const int r0 = blockIdx.x * 128;
    const int cb = blockIdx.y;                 // column half: cols cb*512 + [0,512)

    // stage atom rows -> bf16 LDS (granule = 8 elems = 16B, XOR swizzle)
    #pragma unroll
    for (int s = 0; s < 8; ++s) {
        int G = tid + s * 512;                 // 0..4095 granules
        int row = G >> 5, gc = G & 31;
        int grow = r0 + row;
        union { unsigned short u[8]; uint4 q; } pk;
        if (grow < N_ATOMS) {
            const float4* src = reinterpret_cast<const float4*>(atom + (size_t)grow * 256 + gc * 8);
            float4 v0 = src[0], v1 = src[1];
            pk.u[0]=f2bf(v0.x); pk.u[1]=f2bf(v0.y); pk.u[2]=f2bf(v0.z); pk.u[3]=f2bf(v0.w);
            pk.u[4]=f2bf(v1.x); pk.u[5]=f2bf(v1.y); pk.u[6]=f2bf(v1.z); pk.u[7]=f2bf(v1.w);
        } else {
            pk.q = make_uint4(0u, 0u, 0u, 0u);
        }
        *reinterpret_cast<uint4*>(&sA[row * 256 + ((gc ^ (row & 7)) << 3)]) = pk.q;
    }
    __syncthreads();

    const int lane = tid & 63, wave = tid >> 6;
    const int wr = wave >> 2, wc = wave & 3;   // 2 row-waves x 4 col-waves
    const int l15 = lane & 15, l16 = lane >> 4;

    f32x4 acc[4][8];
    #pragma unroll
    for (int mt = 0; mt < 4; ++mt)
        #pragma unroll
        for (int nt = 0; nt < 8; ++nt) acc[mt][nt] = f32x4{0.f, 0.f, 0.f, 0.f};

    #pragma unroll
    for (int ks = 0; ks < 8; ++ks) {
        bf16x8 af[4];
        #pragma unroll
        for (int mt = 0; mt < 4; ++mt) {
            int row = wr * 64 + mt * 16 + l15;
            int g = ks * 4 + l16;
            af[mt] = *reinterpret_cast<const bf16x8*>(&sA[row * 256 + ((g ^ (row & 7)) << 3)]);
        }
        bf16x8 bfr[8];
        #pragma unroll
        for (int nt = 0; nt < 8; ++nt) {
            int col = cb * 512 + wc * 128 + nt * 16 + l15;
            bfr[nt] = *reinterpret_cast<const bf16x8*>(&Wp1[((size_t)(ks * 4 + l16) * 1024 + col) * 8]);
        }
        #pragma unroll
        for (int mt = 0; mt < 4; ++mt)
            #pragma unroll
            for (int nt = 0; nt < 8; ++nt)
                acc[mt][nt] = __builtin_amdgcn_mfma_f32_16x16x32_bf16(af[mt], bfr[nt], acc[mt][nt], 0, 0, 0);
    }

    #pragma unroll
    for (int nt = 0; nt < 8; ++nt) {
        int col = cb * 512 + wc * 128 + nt * 16 + l15;
        float bias = (col < 512) ? fc_b[col] : 0.f;   // uniform per cb
        #pragma unroll
        for (int mt = 0; mt < 4; ++mt) {
            #pragma unroll
            for (int j = 0; j < 4; ++j) {
                int row = r0 + wr * 64 + mt * 16 + l16 * 4 + j;
                if (row < N_ATOMS)
                    P[(size_t)row * 1024 + col] = f2bf(acc[mt][nt][j] + bias);
            }
        }
    }
}

// ---------------- Kernel 2: fused bond-GEMM + gather-add + LN1 + gate*core + mean + LN2 + residual
__global__ __launch_bounds__(512, 2) void fused_conv(
    const float* __restrict__ atom, const float* __restrict__ bond,
    const int* __restrict__ nbr, const unsigned short* __restrict__ P,
    const unsigned short* __restrict__ Wp3,
    const float* __restrict__ ln1_g, const float* __restrict__ ln1_b,
    const float* __restrict__ ln2_g, const float* __restrict__ ln2_b,
    float* __restrict__ out)
{
    __shared__ unsigned short sA[96 * 128];            // 24KB bond tile (bf16 swizzled)
    __shared__ __align__(16) char sBigRaw[99840];      // pLds ushort[96][520] then tF float[96][260]
    __shared__ float sRed[2][96][4];                   // LN1 cross-wave partials
    __shared__ float sO[8][256];                       // per-atom mean(gate*core)
    __shared__ unsigned short sP1[8 * 512];            // P1 rows for the 8 block atoms
    __shared__ int sNbr[96];

    unsigned short* pLds = reinterpret_cast<unsigned short*>(sBigRaw);
    float* tF = reinterpret_cast<float*>(sBigRaw);

    const int tid = threadIdx.x;
    const int i0 = blockIdx.x * 8;                     // 8 atoms per block, 30000/8 = 3750 exact

    if (tid < 96) sNbr[tid] = nbr[i0 * 12 + tid];

    // stage bond rows -> bf16 LDS, XOR-swizzled granules
    #pragma unroll
    for (int s = 0; s < 3; ++s) {
        int G = tid + s * 512;                         // 0..1535 granules (96 rows x 16)
        int row = G >> 4, gc = G & 15;
        const float4* src = reinterpret_cast<const float4*>(bond + (size_t)(i0 * 12 + row) * 128 + gc * 8);
        float4 v0 = src[0], v1 = src[1];
        union { unsigned short u[8]; uint4 q; } pk;
        pk.u[0]=f2bf(v0.x); pk.u[1]=f2bf(v0.y); pk.u[2]=f2bf(v0.z); pk.u[3]=f2bf(v0.w);
        pk.u[4]=f2bf(v1.x); pk.u[5]=f2bf(v1.y); pk.u[6]=f2bf(v1.z); pk.u[7]=f2bf(v1.w);
        *reinterpret_cast<uint4*>(&sA[row * 128 + ((gc ^ (row & 7)) << 3)]) = pk.q;
    }
    __syncthreads();

    const int lane = tid & 63, wave = tid >> 6;
    const int wr = wave >> 2, wc = wave & 3;           // 2 x 4 waves
    const int l15 = lane & 15, l16 = lane >> 4;

    f32x4 acc[3][8];
    #pragma unroll
    for (int mt = 0; mt < 3; ++mt)
        #pragma unroll
        for (int nt = 0; nt < 8; ++nt) acc[mt][nt] = f32x4{0.f, 0.f, 0.f, 0.f};

    // GEMM: [96,128(bond)] @ Wp3 -> z3 partial. cols: nt<4 gate slice, nt>=4 core slice (same lane pairs a / 256+a)
    #pragma unroll
    for (int ks = 0; ks < 4; ++ks) {
        bf16x8 af[3];
        #pragma unroll
        for (int mt = 0; mt < 3; ++mt) {
            int row = wr * 48 + mt * 16 + l15;
            int g = ks * 4 + l16;
            af[mt] = *reinterpret_cast<const bf16x8*>(&sA[row * 128 + ((g ^ (row & 7)) << 3)]);
        }
        bf16x8 bfr[8];
        #pragma unroll
        for (int nt = 0; nt < 8; ++nt) {
            int col = (nt < 4) ? (wc * 64 + nt * 16 + l15) : (256 + wc * 64 + (nt - 4) * 16 + l15);
            bfr[nt] = *reinterpret_cast<const bf16x8*>(&Wp3[((size_t)(ks * 4 + l16) * 512 + col) * 8]);
        }
        #pragma unroll
        for (int mt = 0; mt < 3; ++mt)
            #pragma unroll
            for (int nt = 0; nt < 8; ++nt)
                acc[mt][nt] = __builtin_amdgcn_mfma_f32_16x16x32_bf16(af[mt], bfr[nt], acc[mt][nt], 0, 0, 0);
    }

    // stage gathered P2 rows (coalesced 16B) and the block's P1 rows into LDS
    #pragma unroll
    for (int s = 0; s < 12; ++s) {
        int G = tid + s * 512;                         // 96 rows x 64 granules
        int r = G >> 6, gc = G & 63;
        *reinterpret_cast<uint4*>(&pLds[r * 520 + gc * 8]) =
            *reinterpret_cast<const uint4*>(&P[(size_t)sNbr[r] * 1024 + 512 + gc * 8]);
    }
    {
        int li = tid >> 6, gc = tid & 63;
        *reinterpret_cast<uint4*>(&sP1[li * 512 + gc * 8]) =
            *reinterpret_cast<const uint4*>(&P[(size_t)(i0 + li) * 1024 + gc * 8]);
    }
    __syncthreads();

    // 3a: add P1 + P2, accumulate LN1 sums, cross-lane then cross-wave reduce
    #pragma unroll
    for (int mt = 0; mt < 3; ++mt) {
        #pragma unroll
        for (int j = 0; j < 4; ++j) {
            const int row = wr * 48 + mt * 16 + l16 * 4 + j;
            const int li = row / 12;
            float s = 0.f, q = 0.f;
            #pragma unroll
            for (int nt = 0; nt < 8; ++nt) {
                const int col = (nt < 4) ? (wc * 64 + nt * 16 + l15) : (256 + wc * 64 + (nt - 4) * 16 + l15);
                float z = acc[mt][nt][j] + bf2f(sP1[li * 512 + col]) + bf2f(pLds[row * 520 + col]);
                acc[mt][nt][j] = z;
                s += z; q += z * z;
            }
            #pragma unroll
            for (int msk = 1; msk <= 8; msk <<= 1) {
                s += __shfl_xor(s, msk, 64);
                q += __shfl_xor(q, msk, 64);
            }
            if (l15 == 0) { sRed[0][row][wc] = s; sRed[1][row][wc] = q; }
        }
    }
    __syncthreads();   // also fences pLds reads before tF overwrites the region

    // 3b: LN1 normalize, gate*core, write t to LDS
    float gg[4], gb[4], cg[4], cb2[4];
    #pragma unroll
    for (int nt = 0; nt < 4; ++nt) {
        int a = wc * 64 + nt * 16 + l15;
        gg[nt] = ln1_g[a];        gb[nt]  = ln1_b[a];
        cg[nt] = ln1_g[256 + a];  cb2[nt] = ln1_b[256 + a];
    }
    #pragma unroll
    for (int mt = 0; mt < 3; ++mt) {
        #pragma unroll
        for (int j = 0; j < 4; ++j) {
            const int row = wr * 48 + mt * 16 + l16 * 4 + j;
            float s4 = sRed[0][row][0] + sRed[0][row][1] + sRed[0][row][2] + sRed[0][row][3];
            float q4 = sRed[1][row][0] + sRed[1][row][1] + sRed[1][row][2] + sRed[1][row][3];
            float mu = s4 * (1.f / 512.f);
            float var = q4 * (1.f / 512.f) - mu * mu;
            float rstd = rsqrtf(var + 1e-5f);
            #pragma unroll
            for (int nt = 0; nt < 4; ++nt) {
                float zg = (acc[mt][nt][j]     - mu) * rstd * gg[nt] + gb[nt];
                float zc = (acc[mt][nt + 4][j] - mu) * rstd * cg[nt] + cb2[nt];
                float gate = 1.f / (1.f + __expf(-zg));
                float core = (zc > 20.f) ? zc : log1pf(__expf(zc));
                tF[row * 260 + wc * 64 + nt * 16 + l15] = gate * core;
            }
        }
    }
    __syncthreads();

    // 3c: mean over the 12 neighbors per atom
    #pragma unroll
    for (int rep = 0; rep < 4; ++rep) {
        int idx = tid + rep * 512;                     // 8 atoms x 256 cols
        int li = idx >> 8, a = idx & 255;
        float ssum = 0.f;
        #pragma unroll
        for (int m = 0; m < 12; ++m) ssum += tF[(li * 12 + m) * 260 + a];
        sO[li][a] = ssum * (1.f / 12.f);
    }
    __syncthreads();

    // 3d: LN2 per atom (one wave per atom) + residual add
    {
        const int li = wave;
        const int gi = i0 + li;
        float v[4]; float s = 0.f, q = 0.f;
        #pragma unroll
        for (int qd = 0; qd < 4; ++qd) {
            v[qd] = sO[li][lane + qd * 64];
            s += v[qd]; q += v[qd] * v[qd];
        }
        #pragma unroll
        for (int msk = 1; msk <= 32; msk <<= 1) {
            s += __shfl_xor(s, msk, 64);
            q += __shfl_xor(q, msk, 64);
        }
        float mu = s * (1.f / 256.f);
        float var = q * (1.f / 256.f) - mu * mu;
        float rstd = rsqrtf(var + 1e-5f);
        #pragma unroll
        for (int qd = 0; qd < 4; ++qd) {
            int a = lane + qd * 64;
            out[(size_t)gi * 256 + a] = atom[(size_t)gi * 256 + a] + (v[qd] - mu) * rstd * ln2_g[a] + ln2_b[a];
        }
    }
}

extern "C" void kernel_launch(void* const* d_in, const int* in_sizes, int n_in,
                              void* d_out, int out_size, void* d_ws, size_t ws_size,
                              hipStream_t stream) {
    const float* atom  = (const float*)d_in[0];
    const float* bond  = (const float*)d_in[1];
    const float* fc_w  = (const float*)d_in[2];
    const float* fc_b  = (const float*)d_in[3];
    const float* ln1_g = (const float*)d_in[4];
    const float* ln1_b = (const float*)d_in[5];
    const float* ln2_g = (const float*)d_in[6];
    const float* ln2_b = (const float*)d_in[7];
    const int*   nbr   = (const int*)d_in[8];

    char* ws = (char*)d_ws;
    unsigned short* P   = (unsigned short*)ws;                          // 61,440,000 B
    unsigned short* Wp1 = (unsigned short*)(ws + 61440000);             // 524,288 B
    unsigned short* Wp3 = (unsigned short*)(ws + 61440000 + 524288);    // 131,072 B
    float* outp = (float*)d_out;

    hipLaunchKernelGGL(pack_weights, dim3(1280), dim3(256), 0, stream, fc_w, Wp1, Wp3);
    hipLaunchKernelGGL(gemm_p, dim3(235, 2), dim3(512), 0, stream, atom, fc_b, Wp1, P);
    hipLaunchKernelGGL(fused_conv, dim3(3750), dim3(512), 0, stream,
                       atom, bond, nbr, P, Wp3, ln1_g, ln1_b, ln2_g, ln2_b, outp);
}

// Round 2
// 610.388 us; speedup vs baseline: 1.0193x; 1.0193x over previous
//
#include <hip/hip_runtime.h>
#include <hip/hip_bf16.h>

#define N_ATOMS 30000
#define M_NBR   12
#define A_DIM   256
#define B_DIM   128

typedef __bf16 bf16x8 __attribute__((ext_vector_type(8)));
typedef float  f32x4  __attribute__((ext_vector_type(4)));

__device__ __forceinline__ unsigned short f2bf(float f) {
    union { float f; unsigned u; } v; v.f = f;
    unsigned r = v.u + 0x7fffu + ((v.u >> 16) & 1u);
    return (unsigned short)(r >> 16);
}
__device__ __forceinline__ float bf2f(unsigned short u) {
    union { unsigned u; float f; } v; v.u = ((unsigned)u) << 16;
    return v.f;
}

// ---------------- Kernel 0: pack fc_w into bf16 fragment-order tables ----------
// Wp1: [32][1024][8]  (K=256 granules g; cols n'<512 -> W[n'][g*8+j] ; n'>=512 -> W[n'-512][256+g*8+j])
// Wp3: [16][512][8]   (K=128 granules;  Wp3[g][n][j] = W[n][512+g*8+j])
__global__ void pack_weights(const float* __restrict__ fc_w,
                             unsigned short* __restrict__ Wp1,
                             unsigned short* __restrict__ Wp3) {
    int idx = blockIdx.x * 256 + threadIdx.x;
    const int n1 = 32 * 1024 * 8;
    if (idx < n1) {
        int j = idx & 7, n = (idx >> 3) & 1023, g = idx >> 13;
        float v = (n < 512) ? fc_w[n * 640 + g * 8 + j]
                            : fc_w[(n - 512) * 640 + 256 + g * 8 + j];
        Wp1[idx] = f2bf(v);
    } else {
        int k = idx - n1;
        if (k < 16 * 512 * 8) {
            int j = k & 7, n = (k >> 3) & 511, g = k >> 12;
            Wp3[k] = f2bf(fc_w[n * 640 + 512 + g * 8 + j]);
        }
    }
}

// ---------------- Kernel 1: P[n][0:512]=W1*atom+b, P[n][512:1024]=W2*atom (bf16) ---
__global__ __launch_bounds__(512, 2) void gemm_p(
    const float* __restrict__ atom, const float* __restrict__ fc_b,
    const unsigned short* __restrict__ Wp1, unsigned short* __restrict__ P)
{
    __shared__ unsigned short sA[128 * 256];   // 64KB, swizzled bf16 A-tile
    const int tid = threadIdx.x;
    const int r0 = blockIdx.x * 128;
    const int cb = blockIdx.y;                 // column half: cols cb*512 + [0,512)

    #pragma unroll
    for (int s = 0; s < 8; ++s) {
        int G = tid + s * 512;                 // 0..4095 granules
        int row = G >> 5, gc = G & 31;
        int grow = r0 + row;
        union { unsigned short u[8]; uint4 q; } pk;
        if (grow < N_ATOMS) {
            const float4* src = reinterpret_cast<const float4*>(atom + (size_t)grow * 256 + gc * 8);
            float4 v0 = src[0], v1 = src[1];
            pk.u[0]=f2bf(v0.x); pk.u[1]=f2bf(v0.y); pk.u[2]=f2bf(v0.z); pk.u[3]=f2bf(v0.w);
            pk.u[4]=f2bf(v1.x); pk.u[5]=f2bf(v1.y); pk.u[6]=f2bf(v1.z); pk.u[7]=f2bf(v1.w);
        } else {
            pk.q = make_uint4(0u, 0u, 0u, 0u);
        }
        *reinterpret_cast<uint4*>(&sA[row * 256 + ((gc ^ (row & 7)) << 3)]) = pk.q;
    }
    __syncthreads();

    const int lane = tid & 63, wave = tid >> 6;
    const int wr = wave >> 2, wcc = wave & 3;  // 2 row-waves x 4 col-waves
    const int l15 = lane & 15, l16 = lane >> 4;

    f32x4 acc[4][8];
    #pragma unroll
    for (int mt = 0; mt < 4; ++mt)
        #pragma unroll
        for (int nt = 0; nt < 8; ++nt) acc[mt][nt] = f32x4{0.f, 0.f, 0.f, 0.f};

    #pragma unroll
    for (int ks = 0; ks < 8; ++ks) {
        bf16x8 af[4];
        #pragma unroll
        for (int mt = 0; mt < 4; ++mt) {
            int row = wr * 64 + mt * 16 + l15;
            int g = ks * 4 + l16;
            af[mt] = *reinterpret_cast<const bf16x8*>(&sA[row * 256 + ((g ^ (row & 7)) << 3)]);
        }
        bf16x8 bfr[8];
        #pragma unroll
        for (int nt = 0; nt < 8; ++nt) {
            int col = cb * 512 + wcc * 128 + nt * 16 + l15;
            bfr[nt] = *reinterpret_cast<const bf16x8*>(&Wp1[((size_t)(ks * 4 + l16) * 1024 + col) * 8]);
        }
        #pragma unroll
        for (int mt = 0; mt < 4; ++mt)
            #pragma unroll
            for (int nt = 0; nt < 8; ++nt)
                acc[mt][nt] = __builtin_amdgcn_mfma_f32_16x16x32_bf16(af[mt], bfr[nt], acc[mt][nt], 0, 0, 0);
    }

    #pragma unroll
    for (int nt = 0; nt < 8; ++nt) {
        int col = cb * 512 + wcc * 128 + nt * 16 + l15;
        float bias = (col < 512) ? fc_b[col] : 0.f;   // uniform per cb
        #pragma unroll
        for (int mt = 0; mt < 4; ++mt) {
            #pragma unroll
            for (int j = 0; j < 4; ++j) {
                int row = r0 + wr * 64 + mt * 16 + l16 * 4 + j;
                if (row < N_ATOMS)
                    P[(size_t)row * 1024 + col] = f2bf(acc[mt][nt][j] + bias);
            }
        }
    }
}

// ---------------- Kernel 2: fused bond-GEMM + gather-add + LN1 + gate*core + mean + LN2 + residual
// 256 threads = 4 waves; 4 atoms (48 bond rows) per block. Wave wc owns 64 gate cols + 64 core cols.
__global__ __launch_bounds__(256, 4) void fused_conv(
    const float* __restrict__ atom, const float* __restrict__ bond,
    const int* __restrict__ nbr, const unsigned short* __restrict__ P,
    const unsigned short* __restrict__ Wp3,
    const float* __restrict__ ln1_g, const float* __restrict__ ln1_b,
    const float* __restrict__ ln2_g, const float* __restrict__ ln2_b,
    float* __restrict__ out)
{
    __shared__ unsigned short sA[48 * 128];    // 12KB bond tile (bf16, swizzled)
    __shared__ unsigned short sP1[4 * 512];    // 4KB P1 rows for the block's 4 atoms
    __shared__ float sRed[2][48][4];           // 1.5KB LN1 cross-wave partials
    __shared__ float sO[4][256];               // 4KB per-atom sum of gate*core
    __shared__ int sNbr[48];

    const int tid = threadIdx.x;
    const int i0 = blockIdx.x * 4;             // 30000/4 = 7500 blocks, exact

    if (tid < 48) sNbr[tid] = nbr[i0 * 12 + tid];
    {   // zero the mean accumulator (LDS is poisoned)
        float* so = &sO[0][0];
        so[tid] = 0.f; so[tid + 256] = 0.f; so[tid + 512] = 0.f; so[tid + 768] = 0.f;
    }

    // stage bond rows -> bf16 LDS, XOR-swizzled 16B granules
    #pragma unroll
    for (int s = 0; s < 3; ++s) {
        int G = tid + s * 256;                 // 768 granules = 48 rows x 16
        int row = G >> 4, gc = G & 15;
        const float4* src = reinterpret_cast<const float4*>(bond + (size_t)(i0 * 12 + row) * 128 + gc * 8);
        float4 v0 = src[0], v1 = src[1];
        union { unsigned short u[8]; uint4 q; } pk;
        pk.u[0]=f2bf(v0.x); pk.u[1]=f2bf(v0.y); pk.u[2]=f2bf(v0.z); pk.u[3]=f2bf(v0.w);
        pk.u[4]=f2bf(v1.x); pk.u[5]=f2bf(v1.y); pk.u[6]=f2bf(v1.z); pk.u[7]=f2bf(v1.w);
        *reinterpret_cast<uint4*>(&sA[row * 128 + ((gc ^ (row & 7)) << 3)]) = pk.q;
    }
    {   // stage P1 rows (4 x 512 bf16): 256 granules, one per thread
        int li = tid >> 6, gc = tid & 63;
        *reinterpret_cast<uint4*>(&sP1[li * 512 + gc * 8]) =
            *reinterpret_cast<const uint4*>(&P[(size_t)(i0 + li) * 1024 + gc * 8]);
    }
    __syncthreads();

    const int lane = tid & 63, wc = tid >> 6;  // wave = col band
    const int l15 = lane & 15, l16 = lane >> 4;

    f32x4 acc[3][8];
    #pragma unroll
    for (int mt = 0; mt < 3; ++mt)
        #pragma unroll
        for (int nt = 0; nt < 8; ++nt) acc[mt][nt] = f32x4{0.f, 0.f, 0.f, 0.f};

    // GEMM: [48,128(bond)] @ Wp3. nt<4 gate cols (a), nt>=4 core cols (256+a): same lane holds the pair.
    #pragma unroll
    for (int ks = 0; ks < 4; ++ks) {
        bf16x8 af[3];
        #pragma unroll
        for (int mt = 0; mt < 3; ++mt) {
            int row = mt * 16 + l15;
            int g = ks * 4 + l16;
            af[mt] = *reinterpret_cast<const bf16x8*>(&sA[row * 128 + ((g ^ (row & 7)) << 3)]);
        }
        bf16x8 bfr[8];
        #pragma unroll
        for (int nt = 0; nt < 8; ++nt) {
            int col = (nt < 4) ? (wc * 64 + nt * 16 + l15) : (256 + wc * 64 + (nt - 4) * 16 + l15);
            bfr[nt] = *reinterpret_cast<const bf16x8*>(&Wp3[((size_t)(ks * 4 + l16) * 512 + col) * 8]);
        }
        #pragma unroll
        for (int mt = 0; mt < 3; ++mt)
            #pragma unroll
            for (int nt = 0; nt < 8; ++nt)
                acc[mt][nt] = __builtin_amdgcn_mfma_f32_16x16x32_bf16(af[mt], bfr[nt], acc[mt][nt], 0, 0, 0);
    }

    // pass 1: z = acc + P1 + P2 (P2 straight from global/L2), accumulate LN1 stats
    #pragma unroll
    for (int mt = 0; mt < 3; ++mt) {
        const int li = (mt * 16 + l16 * 4) / 12;      // 4 | 12 => each j-quad is in one atom
        float p1v[8];
        #pragma unroll
        for (int nt = 0; nt < 8; ++nt) {
            int off = (nt < 4) ? nt * 16 : 256 + (nt - 4) * 16;
            p1v[nt] = bf2f(sP1[li * 512 + wc * 64 + l15 + off]);
        }
        #pragma unroll
        for (int j = 0; j < 4; ++j) {
            const int row = mt * 16 + l16 * 4 + j;
            const unsigned short* p2p = P + (size_t)sNbr[row] * 1024 + 512 + wc * 64 + l15;
            float s = 0.f, q = 0.f;
            #pragma unroll
            for (int nt = 0; nt < 8; ++nt) {
                int off = (nt < 4) ? nt * 16 : 256 + (nt - 4) * 16;
                float z = acc[mt][nt][j] + p1v[nt] + bf2f(p2p[off]);
                acc[mt][nt][j] = z;
                s += z; q = fmaf(z, z, q);
            }
            #pragma unroll
            for (int msk = 1; msk <= 8; msk <<= 1) {
                s += __shfl_xor(s, msk, 64);
                q += __shfl_xor(q, msk, 64);
            }
            if (l15 == 0) { sRed[0][row][wc] = s; sRed[1][row][wc] = q; }
        }
    }
    __syncthreads();

    // pass 2: LN1 normalize, sigmoid*softplus (fast intrinsics), accumulate mean via LDS atomics
    #pragma unroll
    for (int mt = 0; mt < 3; ++mt) {
        const int li = (mt * 16 + l16 * 4) / 12;
        float rstd[4], murs[4];
        #pragma unroll
        for (int j = 0; j < 4; ++j) {
            int row = mt * 16 + l16 * 4 + j;
            float s4 = sRed[0][row][0] + sRed[0][row][1] + sRed[0][row][2] + sRed[0][row][3];
            float q4 = sRed[1][row][0] + sRed[1][row][1] + sRed[1][row][2] + sRed[1][row][3];
            float mu = s4 * (1.f / 512.f);
            float var = q4 * (1.f / 512.f) - mu * mu;
            rstd[j] = __builtin_amdgcn_rsqf(var + 1e-5f);
            murs[j] = mu * rstd[j];
        }
        #pragma unroll
        for (int nt = 0; nt < 4; ++nt) {
            const int a = wc * 64 + nt * 16 + l15;
            const float g1 = ln1_g[a],      b1 = ln1_b[a];
            const float gC = ln1_g[256 + a], bC = ln1_b[256 + a];
            float tq = 0.f;
            #pragma unroll
            for (int j = 0; j < 4; ++j) {
                float zg = fmaf(acc[mt][nt][j], rstd[j], -murs[j]);
                zg = fmaf(zg, g1, b1);
                float zc = fmaf(acc[mt][nt + 4][j], rstd[j], -murs[j]);
                zc = fmaf(zc, gC, bC);
                float gate = __builtin_amdgcn_rcpf(1.f + __expf(-zg));
                float sp   = fmaxf(zc, 0.f) + __logf(1.f + __expf(-fabsf(zc)));
                tq += gate * sp;
            }
            atomicAdd(&sO[li][a], tq);     // 3 contributors per (atom,col)
        }
    }
    __syncthreads();

    // mean /12 + LN2 + residual: wave wc handles atom wc
    {
        const int gi = i0 + wc;
        float v[4]; float s = 0.f, q = 0.f;
        #pragma unroll
        for (int qd = 0; qd < 4; ++qd) {
            v[qd] = sO[wc][lane + qd * 64] * (1.f / 12.f);
            s += v[qd]; q = fmaf(v[qd], v[qd], q);
        }
        #pragma unroll
        for (int msk = 1; msk <= 32; msk <<= 1) {
            s += __shfl_xor(s, msk, 64);
            q += __shfl_xor(q, msk, 64);
        }
        float mu = s * (1.f / 256.f);
        float var = q * (1.f / 256.f) - mu * mu;
        float rstd = __builtin_amdgcn_rsqf(var + 1e-5f);
        #pragma unroll
        for (int qd = 0; qd < 4; ++qd) {
            int a = lane + qd * 64;
            out[(size_t)gi * 256 + a] = atom[(size_t)gi * 256 + a]
                                      + (v[qd] - mu) * rstd * ln2_g[a] + ln2_b[a];
        }
    }
}

extern "C" void kernel_launch(void* const* d_in, const int* in_sizes, int n_in,
                              void* d_out, int out_size, void* d_ws, size_t ws_size,
                              hipStream_t stream) {
    const float* atom  = (const float*)d_in[0];
    const float* bond  = (const float*)d_in[1];
    const float* fc_w  = (const float*)d_in[2];
    const float* fc_b  = (const float*)d_in[3];
    const float* ln1_g = (const float*)d_in[4];
    const float* ln1_b = (const float*)d_in[5];
    const float* ln2_g = (const float*)d_in[6];
    const float* ln2_b = (const float*)d_in[7];
    const int*   nbr   = (const int*)d_in[8];

    char* ws = (char*)d_ws;
    unsigned short* P   = (unsigned short*)ws;                          // 61,440,000 B
    unsigned short* Wp1 = (unsigned short*)(ws + 61440000);             // 524,288 B
    unsigned short* Wp3 = (unsigned short*)(ws + 61440000 + 524288);    // 131,072 B
    float* outp = (float*)d_out;

    hipLaunchKernelGGL(pack_weights, dim3(1280), dim3(256), 0, stream, fc_w, Wp1, Wp3);
    hipLaunchKernelGGL(gemm_p, dim3(235, 2), dim3(512), 0, stream, atom, fc_b, Wp1, P);
    hipLaunchKernelGGL(fused_conv, dim3(7500), dim3(256), 0, stream,
                       atom, bond, nbr, P, Wp3, ln1_g, ln1_b, ln2_g, ln2_b, outp);
}

// Round 3
// 329.369 us; speedup vs baseline: 1.8889x; 1.8532x over previous
//
#include <hip/hip_runtime.h>
#include <hip/hip_bf16.h>

#define N_ATOMS 30000
#define M_NBR   12
#define A_DIM   256
#define B_DIM   128

typedef __bf16 bf16x8 __attribute__((ext_vector_type(8)));
typedef float  f32x4  __attribute__((ext_vector_type(4)));

__device__ __forceinline__ unsigned short f2bf(float f) {
    union { float f; unsigned u; } v; v.f = f;
    unsigned r = v.u + 0x7fffu + ((v.u >> 16) & 1u);
    return (unsigned short)(r >> 16);
}
__device__ __forceinline__ float bf2f(unsigned short u) {
    union { unsigned u; float f; } v; v.u = ((unsigned)u) << 16;
    return v.f;
}

// packed per-row address for z-column c (0..511):
// layout [wcband:4][l15:16][slot:8]; gate cols (c<256) -> slot 0..3, core -> slot 4..7.
// Consumer lane (wc,l15) then reads its 8 values as ONE contiguous 16B load.
__device__ __forceinline__ int packAddr(int c) {
    int cc = c & 255;
    int slot = ((cc & 63) >> 4) + ((c >> 8) << 2);   // +4 for the core half
    return (cc >> 6) * 128 + (cc & 15) * 8 + slot;
}

// ---------------- Kernel 0: pack fc_w into bf16 fragment-order tables ----------
// Wp1: [32][1024][8]  (K=256 granules g; cols n'<512 -> W[n'][g*8+j] ; n'>=512 -> W[n'-512][256+g*8+j])
// Wp3: [16][512][8]   (K=128 granules;  Wp3[g][n][j] = W[n][512+g*8+j])
__global__ void pack_weights(const float* __restrict__ fc_w,
                             unsigned short* __restrict__ Wp1,
                             unsigned short* __restrict__ Wp3) {
    int idx = blockIdx.x * 256 + threadIdx.x;
    const int n1 = 32 * 1024 * 8;
    if (idx < n1) {
        int j = idx & 7, n = (idx >> 3) & 1023, g = idx >> 13;
        float v = (n < 512) ? fc_w[n * 640 + g * 8 + j]
                            : fc_w[(n - 512) * 640 + 256 + g * 8 + j];
        Wp1[idx] = f2bf(v);
    } else {
        int k = idx - n1;
        if (k < 16 * 512 * 8) {
            int j = k & 7, n = (k >> 3) & 511, g = k >> 12;
            Wp3[k] = f2bf(fc_w[n * 640 + 512 + g * 8 + j]);
        }
    }
}

// ---------------- Kernel 1: P1 = W1*atom + b, P2 = W2*atom, stored PACKED (bf16) ---
// P row layout (1024 ushorts): [0:512) = P1 packed, [512:1024) = P2 packed.
__global__ __launch_bounds__(512, 2) void gemm_p(
    const float* __restrict__ atom, const float* __restrict__ fc_b,
    const unsigned short* __restrict__ Wp1, unsigned short* __restrict__ P)
{
    __shared__ unsigned short sA[128 * 256];   // 64KB, swizzled bf16 A-tile
    const int tid = threadIdx.x;
    const int r0 = blockIdx.x * 128;
    const int cb = blockIdx.y;                 // 0: W1 half (cols 0-511), 1: W2 half

    #pragma unroll
    for (int s = 0; s < 8; ++s) {
        int G = tid + s * 512;                 // 0..4095 granules
        int row = G >> 5, gc = G & 31;
        int grow = r0 + row;
        union { unsigned short u[8]; uint4 q; } pk;
        if (grow < N_ATOMS) {
            const float4* src = reinterpret_cast<const float4*>(atom + (size_t)grow * 256 + gc * 8);
            float4 v0 = src[0], v1 = src[1];
            pk.u[0]=f2bf(v0.x); pk.u[1]=f2bf(v0.y); pk.u[2]=f2bf(v0.z); pk.u[3]=f2bf(v0.w);
            pk.u[4]=f2bf(v1.x); pk.u[5]=f2bf(v1.y); pk.u[6]=f2bf(v1.z); pk.u[7]=f2bf(v1.w);
        } else {
            pk.q = make_uint4(0u, 0u, 0u, 0u);
        }
        *reinterpret_cast<uint4*>(&sA[row * 256 + ((gc ^ (row & 7)) << 3)]) = pk.q;
    }
    __syncthreads();

    const int lane = tid & 63, wave = tid >> 6;
    const int wr = wave >> 2, wcc = wave & 3;  // 2 row-waves x 4 col-waves
    const int l15 = lane & 15, l16 = lane >> 4;

    f32x4 acc[4][8];
    #pragma unroll
    for (int mt = 0; mt < 4; ++mt)
        #pragma unroll
        for (int nt = 0; nt < 8; ++nt) acc[mt][nt] = f32x4{0.f, 0.f, 0.f, 0.f};

    #pragma unroll
    for (int ks = 0; ks < 8; ++ks) {
        bf16x8 af[4];
        #pragma unroll
        for (int mt = 0; mt < 4; ++mt) {
            int row = wr * 64 + mt * 16 + l15;
            int g = ks * 4 + l16;
            af[mt] = *reinterpret_cast<const bf16x8*>(&sA[row * 256 + ((g ^ (row & 7)) << 3)]);
        }
        bf16x8 bfr[8];
        #pragma unroll
        for (int nt = 0; nt < 8; ++nt) {
            int col = cb * 512 + wcc * 128 + nt * 16 + l15;
            bfr[nt] = *reinterpret_cast<const bf16x8*>(&Wp1[((size_t)(ks * 4 + l16) * 1024 + col) * 8]);
        }
        #pragma unroll
        for (int mt = 0; mt < 4; ++mt)
            #pragma unroll
            for (int nt = 0; nt < 8; ++nt)
                acc[mt][nt] = __builtin_amdgcn_mfma_f32_16x16x32_bf16(af[mt], bfr[nt], acc[mt][nt], 0, 0, 0);
    }

    #pragma unroll
    for (int nt = 0; nt < 8; ++nt) {
        int zcol = wcc * 128 + nt * 16 + l15;          // z-column in [0,512)
        float bias = (cb == 0) ? fc_b[zcol] : 0.f;     // bias folded into P1 only
        int pa = cb * 512 + packAddr(zcol);
        #pragma unroll
        for (int mt = 0; mt < 4; ++mt) {
            #pragma unroll
            for (int j = 0; j < 4; ++j) {
                int row = r0 + wr * 64 + mt * 16 + l16 * 4 + j;
                if (row < N_ATOMS)
                    P[(size_t)row * 1024 + pa] = f2bf(acc[mt][nt][j] + bias);
            }
        }
    }
}

// ---------------- Kernel 2: fused bond-GEMM + gather-add + LN1 + gate*core + mean + LN2 + residual
// 256 threads = 4 waves; 4 atoms (48 bond rows) per block. Wave wc owns 64 gate cols + 64 core cols.
__global__ __launch_bounds__(256, 2) void fused_conv(
    const float* __restrict__ atom, const float* __restrict__ bond,
    const int* __restrict__ nbr, const unsigned short* __restrict__ P,
    const unsigned short* __restrict__ Wp3,
    const float* __restrict__ ln1_g, const float* __restrict__ ln1_b,
    const float* __restrict__ ln2_g, const float* __restrict__ ln2_b,
    float* __restrict__ out)
{
    __shared__ unsigned short sA[48 * 128];    // 12KB bond tile (bf16, swizzled)
    __shared__ float sRed[2][48][4];           // 1.5KB LN1 cross-wave partials
    __shared__ float sO[4][256];               // 4KB per-atom sum of gate*core
    __shared__ int sNbr[48];

    const int tid = threadIdx.x;
    const int i0 = blockIdx.x * 4;             // 30000/4 = 7500 blocks, exact

    if (tid < 48) sNbr[tid] = nbr[i0 * 12 + tid];
    {   // zero the mean accumulator (LDS is poisoned)
        float* so = &sO[0][0];
        so[tid] = 0.f; so[tid + 256] = 0.f; so[tid + 512] = 0.f; so[tid + 768] = 0.f;
    }

    // stage bond rows -> bf16 LDS, XOR-swizzled 16B granules
    #pragma unroll
    for (int s = 0; s < 3; ++s) {
        int G = tid + s * 256;                 // 768 granules = 48 rows x 16
        int row = G >> 4, gc = G & 15;
        const float4* src = reinterpret_cast<const float4*>(bond + (size_t)(i0 * 12 + row) * 128 + gc * 8);
        float4 v0 = src[0], v1 = src[1];
        union { unsigned short u[8]; uint4 q; } pk;
        pk.u[0]=f2bf(v0.x); pk.u[1]=f2bf(v0.y); pk.u[2]=f2bf(v0.z); pk.u[3]=f2bf(v0.w);
        pk.u[4]=f2bf(v1.x); pk.u[5]=f2bf(v1.y); pk.u[6]=f2bf(v1.z); pk.u[7]=f2bf(v1.w);
        *reinterpret_cast<uint4*>(&sA[row * 128 + ((gc ^ (row & 7)) << 3)]) = pk.q;
    }
    __syncthreads();

    const int lane = tid & 63, wc = tid >> 6;  // wave = col band
    const int l15 = lane & 15, l16 = lane >> 4;

    f32x4 acc[3][8];
    #pragma unroll
    for (int mt = 0; mt < 3; ++mt)
        #pragma unroll
        for (int nt = 0; nt < 8; ++nt) acc[mt][nt] = f32x4{0.f, 0.f, 0.f, 0.f};

    // GEMM: [48,128(bond)] @ Wp3. nt<4 gate cols (a), nt>=4 core cols (256+a): same lane holds the pair.
    #pragma unroll
    for (int ks = 0; ks < 4; ++ks) {
        bf16x8 af[3];
        #pragma unroll
        for (int mt = 0; mt < 3; ++mt) {
            int row = mt * 16 + l15;
            int g = ks * 4 + l16;
            af[mt] = *reinterpret_cast<const bf16x8*>(&sA[row * 128 + ((g ^ (row & 7)) << 3)]);
        }
        bf16x8 bfr[8];
        #pragma unroll
        for (int nt = 0; nt < 8; ++nt) {
            int col = (nt < 4) ? (wc * 64 + nt * 16 + l15) : (256 + wc * 64 + (nt - 4) * 16 + l15);
            bfr[nt] = *reinterpret_cast<const bf16x8*>(&Wp3[((size_t)(ks * 4 + l16) * 512 + col) * 8]);
        }
        #pragma unroll
        for (int mt = 0; mt < 3; ++mt)
            #pragma unroll
            for (int nt = 0; nt < 8; ++nt)
                acc[mt][nt] = __builtin_amdgcn_mfma_f32_16x16x32_bf16(af[mt], bfr[nt], acc[mt][nt], 0, 0, 0);
    }

    // pass 1: z = acc + P1 + P2 (both read as ONE 16B packed load per lane), LN1 stats
    #pragma unroll
    for (int mt = 0; mt < 3; ++mt) {
        const int li = (mt * 16 + l16 * 4) / 12;      // 4 | 12 => each j-quad is in one atom
        union { unsigned short u[8]; uint4 q; } p1;
        p1.q = *reinterpret_cast<const uint4*>(&P[(size_t)(i0 + li) * 1024 + wc * 128 + l15 * 8]);
        union { unsigned short u[8]; uint4 q; } p2[4];
        #pragma unroll
        for (int j = 0; j < 4; ++j) {
            const int row = mt * 16 + l16 * 4 + j;
            p2[j].q = *reinterpret_cast<const uint4*>(&P[(size_t)sNbr[row] * 1024 + 512 + wc * 128 + l15 * 8]);
        }
        #pragma unroll
        for (int j = 0; j < 4; ++j) {
            const int row = mt * 16 + l16 * 4 + j;
            float s = 0.f, q = 0.f;
            #pragma unroll
            for (int nt = 0; nt < 8; ++nt) {
                float z = acc[mt][nt][j] + bf2f(p1.u[nt]) + bf2f(p2[j].u[nt]);
                acc[mt][nt][j] = z;
                s += z; q = fmaf(z, z, q);
            }
            #pragma unroll
            for (int msk = 1; msk <= 8; msk <<= 1) {
                s += __shfl_xor(s, msk, 64);
                q += __shfl_xor(q, msk, 64);
            }
            if (l15 == 0) { sRed[0][row][wc] = s; sRed[1][row][wc] = q; }
        }
    }
    __syncthreads();

    // pass 2: LN1 normalize, sigmoid*softplus (fast intrinsics), accumulate mean via LDS atomics
    #pragma unroll
    for (int mt = 0; mt < 3; ++mt) {
        const int li = (mt * 16 + l16 * 4) / 12;
        float rstd[4], murs[4];
        #pragma unroll
        for (int j = 0; j < 4; ++j) {
            int row = mt * 16 + l16 * 4 + j;
            float s4 = sRed[0][row][0] + sRed[0][row][1] + sRed[0][row][2] + sRed[0][row][3];
            float q4 = sRed[1][row][0] + sRed[1][row][1] + sRed[1][row][2] + sRed[1][row][3];
            float mu = s4 * (1.f / 512.f);
            float var = q4 * (1.f / 512.f) - mu * mu;
            rstd[j] = __builtin_amdgcn_rsqf(var + 1e-5f);
            murs[j] = mu * rstd[j];
        }
        #pragma unroll
        for (int nt = 0; nt < 4; ++nt) {
            const int a = wc * 64 + nt * 16 + l15;
            const float g1 = ln1_g[a],       b1 = ln1_b[a];
            const float gC = ln1_g[256 + a], bC = ln1_b[256 + a];
            float tq = 0.f;
            #pragma unroll
            for (int j = 0; j < 4; ++j) {
                float zg = fmaf(acc[mt][nt][j], rstd[j], -murs[j]);
                zg = fmaf(zg, g1, b1);
                float zc = fmaf(acc[mt][nt + 4][j], rstd[j], -murs[j]);
                zc = fmaf(zc, gC, bC);
                float gate = __builtin_amdgcn_rcpf(1.f + __expf(-zg));
                float sp   = fmaxf(zc, 0.f) + __logf(1.f + __expf(-fabsf(zc)));
                tq += gate * sp;
            }
            atomicAdd(&sO[li][a], tq);     // 3 contributors per (atom,col)
        }
    }
    __syncthreads();

    // mean /12 + LN2 + residual: wave wc handles atom wc
    {
        const int gi = i0 + wc;
        float v[4]; float s = 0.f, q = 0.f;
        #pragma unroll
        for (int qd = 0; qd < 4; ++qd) {
            v[qd] = sO[wc][lane + qd * 64] * (1.f / 12.f);
            s += v[qd]; q = fmaf(v[qd], v[qd], q);
        }
        #pragma unroll
        for (int msk = 1; msk <= 32; msk <<= 1) {
            s += __shfl_xor(s, msk, 64);
            q += __shfl_xor(q, msk, 64);
        }
        float mu = s * (1.f / 256.f);
        float var = q * (1.f / 256.f) - mu * mu;
        float rstd = __builtin_amdgcn_rsqf(var + 1e-5f);
        #pragma unroll
        for (int qd = 0; qd < 4; ++qd) {
            int a = lane + qd * 64;
            out[(size_t)gi * 256 + a] = atom[(size_t)gi * 256 + a]
                                      + (v[qd] - mu) * rstd * ln2_g[a] + ln2_b[a];
        }
    }
}

extern "C" void kernel_launch(void* const* d_in, const int* in_sizes, int n_in,
                              void* d_out, int out_size, void* d_ws, size_t ws_size,
                              hipStream_t stream) {
    const float* atom  = (const float*)d_in[0];
    const float* bond  = (const float*)d_in[1];
    const float* fc_w  = (const float*)d_in[2];
    const float* fc_b  = (const float*)d_in[3];
    const float* ln1_g = (const float*)d_in[4];
    const float* ln1_b = (const float*)d_in[5];
    const float* ln2_g = (const float*)d_in[6];
    const float* ln2_b = (const float*)d_in[7];
    const int*   nbr   = (const int*)d_in[8];

    char* ws = (char*)d_ws;
    unsigned short* P   = (unsigned short*)ws;                          // 61,440,000 B
    unsigned short* Wp1 = (unsigned short*)(ws + 61440000);             // 524,288 B
    unsigned short* Wp3 = (unsigned short*)(ws + 61440000 + 524288);    // 131,072 B
    float* outp = (float*)d_out;

    hipLaunchKernelGGL(pack_weights, dim3(1280), dim3(256), 0, stream, fc_w, Wp1, Wp3);
    hipLaunchKernelGGL(gemm_p, dim3(235, 2), dim3(512), 0, stream, atom, fc_b, Wp1, P);
    hipLaunchKernelGGL(fused_conv, dim3(7500), dim3(256), 0, stream,
                       atom, bond, nbr, P, Wp3, ln1_g, ln1_b, ln2_g, ln2_b, outp);
}